// Round 1
// baseline (1155.948 us; speedup 1.0000x reference)
//
#include <hip/hip_runtime.h>
#include <math.h>

#define BH    32      // B*H
#define NSEQ  8192
#define DDIM  64
#define NPROJ 7
#define BLK   256     // BLOCK_SIZE == SAMPLE_SIZE == query block size
#define NB    32      // NSEQ / BLK

// ---------------------------------------------------------------------------
// Kernel 1: LSH hash. bucket = code ^ (code>>1) where code = sum(bit_r << r),
// bit_r = (x . proj[:,r]) > 0.  fp64 accumulation to make sign decisions
// effectively exact (borderline signs are the only sort-mismatch hazard).
// ---------------------------------------------------------------------------
__global__ void hash_kernel(const float* __restrict__ query,
                            const float* __restrict__ key,
                            const float* __restrict__ proj,     // [64][7]
                            int* __restrict__ buckets)          // [2][BH*NSEQ]
{
    const float* x = (blockIdx.y == 0) ? query : key;
    const int row0 = blockIdx.x * 64;
    const int t = threadIdx.x;                 // 0..255

    __shared__ float tile[64][65];             // +1 pad: (t+d)%32 banks, conflict-free
    __shared__ float pd[64 * NPROJ];

    for (int i = t; i < 64 * NPROJ; i += 256) pd[i] = proj[i];

    const float4* src = (const float4*)(x + (size_t)row0 * DDIM);
    #pragma unroll
    for (int i = 0; i < 4; ++i) {
        int idx = t + i * 256;                 // f4 index 0..1023
        int r = idx >> 4, c4 = idx & 15;
        float4 v = src[r * 16 + c4];
        tile[r][c4 * 4 + 0] = v.x;
        tile[r][c4 * 4 + 1] = v.y;
        tile[r][c4 * 4 + 2] = v.z;
        tile[r][c4 * 4 + 3] = v.w;
    }
    __syncthreads();

    if (t < 64) {
        double acc[NPROJ];
        #pragma unroll
        for (int r = 0; r < NPROJ; ++r) acc[r] = 0.0;
        for (int d = 0; d < 64; ++d) {
            double xv = (double)tile[t][d];
            #pragma unroll
            for (int r = 0; r < NPROJ; ++r)
                acc[r] += xv * (double)pd[d * NPROJ + r];
        }
        int code = 0;
        #pragma unroll
        for (int r = 0; r < NPROJ; ++r)
            if (acc[r] > 0.0) code |= (1 << r);
        int bucket = code ^ (code >> 1);       // Gray-code perm
        buckets[(size_t)blockIdx.y * (BH * NSEQ) + row0 + t] = bucket;
    }
}

// ---------------------------------------------------------------------------
// Kernel 2: stable counting sort over 128 bucket values, one wave per (b,h).
// Thread t owns contiguous chunk [t*128, (t+1)*128): per-(bucket,thread)
// histogram -> bucket-major/thread-major exclusive prefix -> stable scatter.
// ---------------------------------------------------------------------------
__global__ void sort_kernel(const int* __restrict__ buckets,   // [2][BH*NSEQ]
                            int* __restrict__ q_idx,           // [BH*NSEQ]
                            int* __restrict__ k_idx)           // [BH*NSEQ]
{
    const int bh = blockIdx.x;
    const int t = threadIdx.x;                 // 0..63
    const int* b = buckets + (size_t)blockIdx.y * (BH * NSEQ) + (size_t)bh * NSEQ;
    int* out = ((blockIdx.y == 0) ? q_idx : k_idx) + (size_t)bh * NSEQ;

    __shared__ unsigned int cnt[128 * 64];
    __shared__ unsigned int rowsum[128];
    __shared__ unsigned int base[128];

    for (int v = 0; v < 128; ++v) cnt[v * 64 + t] = 0;
    __syncthreads();

    const int CH = NSEQ / 64;                  // 128 elements per thread
    const int i0 = t * CH;
    for (int j = 0; j < CH; ++j) {
        int v = b[i0 + j];
        cnt[v * 64 + t]++;
    }
    __syncthreads();

    for (int v = t; v < 128; v += 64) {
        unsigned int s = 0;
        for (int tt = 0; tt < 64; ++tt) s += cnt[v * 64 + tt];
        rowsum[v] = s;
    }
    __syncthreads();

    if (t == 0) {
        unsigned int acc = 0;
        for (int v = 0; v < 128; ++v) { base[v] = acc; acc += rowsum[v]; }
    }
    __syncthreads();

    for (int v = t; v < 128; v += 64) {
        unsigned int acc = base[v];
        for (int tt = 0; tt < 64; ++tt) {
            unsigned int c = cnt[v * 64 + tt];
            cnt[v * 64 + tt] = acc;
            acc += c;
        }
    }
    __syncthreads();

    for (int j = 0; j < CH; ++j) {
        int v = b[i0 + j];
        unsigned int pos = cnt[v * 64 + t]++;
        out[pos] = i0 + j;                     // stable: ascending index order
    }
}

// ---------------------------------------------------------------------------
// Kernel 3: fused block-diagonal + sampled-residual attention.
// One thread per sorted query row; joint online softmax over
// {diag block keys} U {sampled keys, logits + J, in-block masked}, which is
// algebraically identical to the reference's logaddexp combine.
// ---------------------------------------------------------------------------
__global__ __launch_bounds__(256) void attn_kernel(
        const float* __restrict__ query,
        const float* __restrict__ key,
        const float* __restrict__ value,
        const int* __restrict__ sampled,       // [BH][256]
        const int* __restrict__ q_idx,         // [BH][NSEQ]
        const int* __restrict__ k_idx,         // [BH][NSEQ]
        float* __restrict__ outp)              // [BH][NSEQ][64]
{
    const int qb = blockIdx.x;                 // 0..31 query block (sorted order)
    const int bh = blockIdx.y;                 // 0..31
    const int t  = threadIdx.x;                // 0..255 query row within block

    __shared__ float4 Kc[64 * 16];             // 64-key chunk of K
    __shared__ float4 Vc[64 * 16];             // 64-key chunk of V
    __shared__ int s_ko[BLK];                  // sampled keys: original rows
    __shared__ int s_blk[BLK];                 // sampled keys: their block id
    __shared__ int s_kd[BLK];                  // diag keys: original rows

    const size_t bhN = (size_t)bh * NSEQ;

    int ss = sampled[bh * BLK + t];
    s_ko[t]  = k_idx[bhN + ss];
    s_blk[t] = ss >> 8;                        // sampled_set // BLOCK_SIZE
    s_kd[t]  = k_idx[bhN + qb * BLK + t];

    const int qi = q_idx[bhN + qb * BLK + t];  // original query row (for unsort)
    float q[64];
    {
        const float4* qp = (const float4*)(query + (bhN + qi) * DDIM);
        #pragma unroll
        for (int i = 0; i < 16; ++i) {
            float4 v = qp[i];
            q[4 * i + 0] = v.x; q[4 * i + 1] = v.y;
            q[4 * i + 2] = v.z; q[4 * i + 3] = v.w;
        }
    }
    __syncthreads();

    // sampled_cnt is block-uniform: count in-block samples
    int cnt_in = 0;
    for (int s = 0; s < BLK; ++s) cnt_in += (s_blk[s] == qb) ? 1 : 0;
    const float J = __logf((float)(NSEQ - BLK) / (float)(BLK - cnt_in));

    const float scale = 0.125f;                // d^-0.5
    float m = -INFINITY;
    float l = 0.0f;
    float acc[64];
    #pragma unroll
    for (int j = 0; j < 64; ++j) acc[j] = 0.0f;

    for (int stage = 0; stage < 2; ++stage) {
        for (int ch = 0; ch < 4; ++ch) {
            __syncthreads();
            // stage 64 K rows + 64 V rows (gathered) into LDS
            #pragma unroll
            for (int i = 0; i < 4; ++i) {
                int idx = t + i * 256;         // 0..1023
                int r = idx >> 4, c4 = idx & 15;
                int ko = (stage == 0) ? s_kd[ch * 64 + r] : s_ko[ch * 64 + r];
                Kc[r * 16 + c4] = ((const float4*)(key   + (bhN + ko) * DDIM))[c4];
                Vc[r * 16 + c4] = ((const float4*)(value + (bhN + ko) * DDIM))[c4];
            }
            __syncthreads();

            for (int c = 0; c < 64; ++c) {
                if (stage == 1 && s_blk[ch * 64 + c] == qb) continue; // masked (uniform)
                float sp0 = 0.f, sp1 = 0.f, sp2 = 0.f, sp3 = 0.f;
                #pragma unroll
                for (int i = 0; i < 16; i += 4) {
                    float4 k0 = Kc[c * 16 + i + 0];
                    float4 k1 = Kc[c * 16 + i + 1];
                    float4 k2 = Kc[c * 16 + i + 2];
                    float4 k3 = Kc[c * 16 + i + 3];
                    sp0 = fmaf(q[4*(i+0)+0], k0.x, sp0); sp0 = fmaf(q[4*(i+0)+1], k0.y, sp0);
                    sp0 = fmaf(q[4*(i+0)+2], k0.z, sp0); sp0 = fmaf(q[4*(i+0)+3], k0.w, sp0);
                    sp1 = fmaf(q[4*(i+1)+0], k1.x, sp1); sp1 = fmaf(q[4*(i+1)+1], k1.y, sp1);
                    sp1 = fmaf(q[4*(i+1)+2], k1.z, sp1); sp1 = fmaf(q[4*(i+1)+3], k1.w, sp1);
                    sp2 = fmaf(q[4*(i+2)+0], k2.x, sp2); sp2 = fmaf(q[4*(i+2)+1], k2.y, sp2);
                    sp2 = fmaf(q[4*(i+2)+2], k2.z, sp2); sp2 = fmaf(q[4*(i+2)+3], k2.w, sp2);
                    sp3 = fmaf(q[4*(i+3)+0], k3.x, sp3); sp3 = fmaf(q[4*(i+3)+1], k3.y, sp3);
                    sp3 = fmaf(q[4*(i+3)+2], k3.z, sp3); sp3 = fmaf(q[4*(i+3)+3], k3.w, sp3);
                }
                float sv = ((sp0 + sp1) + (sp2 + sp3)) * scale;
                if (stage == 1) sv += J;       // sampled-mass rescale, folded into logit

                float mn = fmaxf(m, sv);
                float f = __expf(m - mn);      // m=-inf first iter -> f=0
                float p = __expf(sv - mn);
                l = l * f + p;
                #pragma unroll
                for (int i = 0; i < 16; ++i) {
                    float4 vv = Vc[c * 16 + i];
                    acc[4*i+0] = fmaf(acc[4*i+0], f, p * vv.x);
                    acc[4*i+1] = fmaf(acc[4*i+1], f, p * vv.y);
                    acc[4*i+2] = fmaf(acc[4*i+2], f, p * vv.z);
                    acc[4*i+3] = fmaf(acc[4*i+3], f, p * vv.w);
                }
                m = mn;
            }
        }
    }

    const float inv = 1.0f / l;
    float4* op = (float4*)(outp + (bhN + qi) * DDIM);   // scatter = un-sort
    #pragma unroll
    for (int i = 0; i < 16; ++i)
        op[i] = make_float4(acc[4*i+0] * inv, acc[4*i+1] * inv,
                            acc[4*i+2] * inv, acc[4*i+3] * inv);
}

// ---------------------------------------------------------------------------
extern "C" void kernel_launch(void* const* d_in, const int* in_sizes, int n_in,
                              void* d_out, int out_size, void* d_ws, size_t ws_size,
                              hipStream_t stream) {
    (void)in_sizes; (void)n_in; (void)out_size; (void)ws_size;
    const float* query = (const float*)d_in[0];
    const float* key   = (const float*)d_in[1];
    const float* value = (const float*)d_in[2];
    const float* proj  = (const float*)d_in[3];
    const int* sampled = (const int*)d_in[4];
    float* out = (float*)d_out;

    int* buckets = (int*)d_ws;                 // [2][BH*NSEQ]  (2 MB)
    int* q_idx   = buckets + 2 * BH * NSEQ;    // [BH*NSEQ]     (1 MB)
    int* k_idx   = q_idx + BH * NSEQ;          // [BH*NSEQ]     (1 MB)

    hash_kernel<<<dim3(BH * NSEQ / 64, 2), 256, 0, stream>>>(query, key, proj, buckets);
    sort_kernel<<<dim3(BH, 2), 64, 0, stream>>>(buckets, q_idx, k_idx);
    attn_kernel<<<dim3(NB, BH), 256, 0, stream>>>(query, key, value, sampled,
                                                  q_idx, k_idx, out);
}

// Round 2
// 303.647 us; speedup vs baseline: 3.8069x; 3.8069x over previous
//
#include <hip/hip_runtime.h>
#include <math.h>

#define BH    32      // B*H
#define NSEQ  8192
#define DDIM  64
#define NPROJ 7
#define BLK   256
#define NB    32      // NSEQ / BLK
#define PITCH 72      // f16 row pitch (16B-aligned: 144 B), spreads b128 reads

typedef _Float16 v8h __attribute__((ext_vector_type(8)));
typedef float    v4f __attribute__((ext_vector_type(4)));

// ---------------------------------------------------------------------------
// Kernel 1: LSH hash (fp64 sign decisions; Gray code = i ^ (i>>1)).
// ---------------------------------------------------------------------------
__global__ void hash_kernel(const float* __restrict__ query,
                            const float* __restrict__ key,
                            const float* __restrict__ proj,     // [64][7]
                            int* __restrict__ buckets)          // [2][BH*NSEQ]
{
    const float* x = (blockIdx.y == 0) ? query : key;
    const int row0 = blockIdx.x * 64;
    const int t = threadIdx.x;

    __shared__ float tile[64][65];
    __shared__ float pd[64 * NPROJ];

    for (int i = t; i < 64 * NPROJ; i += 256) pd[i] = proj[i];

    const float4* src = (const float4*)(x + (size_t)row0 * DDIM);
    #pragma unroll
    for (int i = 0; i < 4; ++i) {
        int idx = t + i * 256;
        int r = idx >> 4, c4 = idx & 15;
        float4 v = src[r * 16 + c4];
        tile[r][c4 * 4 + 0] = v.x;
        tile[r][c4 * 4 + 1] = v.y;
        tile[r][c4 * 4 + 2] = v.z;
        tile[r][c4 * 4 + 3] = v.w;
    }
    __syncthreads();

    if (t < 64) {
        double acc[NPROJ];
        #pragma unroll
        for (int r = 0; r < NPROJ; ++r) acc[r] = 0.0;
        for (int d = 0; d < 64; ++d) {
            double xv = (double)tile[t][d];
            #pragma unroll
            for (int r = 0; r < NPROJ; ++r)
                acc[r] += xv * (double)pd[d * NPROJ + r];
        }
        int code = 0;
        #pragma unroll
        for (int r = 0; r < NPROJ; ++r)
            if (acc[r] > 0.0) code |= (1 << r);
        buckets[(size_t)blockIdx.y * (BH * NSEQ) + row0 + t] = code ^ (code >> 1);
    }
}

// ---------------------------------------------------------------------------
// Kernel 2: stable counting sort, one wave per (b,h) per tensor.
// ---------------------------------------------------------------------------
__global__ void sort_kernel(const int* __restrict__ buckets,
                            int* __restrict__ q_idx,
                            int* __restrict__ k_idx)
{
    const int bh = blockIdx.x;
    const int t = threadIdx.x;                 // 0..63
    const int* b = buckets + (size_t)blockIdx.y * (BH * NSEQ) + (size_t)bh * NSEQ;
    int* out = ((blockIdx.y == 0) ? q_idx : k_idx) + (size_t)bh * NSEQ;

    __shared__ unsigned int cnt[128 * 64];
    __shared__ unsigned int rowsum[128];
    __shared__ unsigned int base[128];

    for (int v = 0; v < 128; ++v) cnt[v * 64 + t] = 0;
    __syncthreads();

    const int CH = NSEQ / 64;
    const int i0 = t * CH;
    for (int j = 0; j < CH; ++j) cnt[b[i0 + j] * 64 + t]++;
    __syncthreads();

    for (int v = t; v < 128; v += 64) {
        unsigned int s = 0;
        for (int tt = 0; tt < 64; ++tt) s += cnt[v * 64 + tt];
        rowsum[v] = s;
    }
    __syncthreads();

    if (t == 0) {
        unsigned int acc = 0;
        for (int v = 0; v < 128; ++v) { base[v] = acc; acc += rowsum[v]; }
    }
    __syncthreads();

    for (int v = t; v < 128; v += 64) {
        unsigned int acc = base[v];
        for (int tt = 0; tt < 64; ++tt) {
            unsigned int c = cnt[v * 64 + tt];
            cnt[v * 64 + tt] = acc;
            acc += c;
        }
    }
    __syncthreads();

    for (int j = 0; j < CH; ++j) {
        int v = b[i0 + j];
        out[cnt[v * 64 + t]++] = i0 + j;
    }
}

// ---------------------------------------------------------------------------
// Kernel 3: MFMA attention. Per block: 256 sorted queries x 512 keys
// (256 diag + 256 sampled). f16 16x16x32 MFMA, fp32 acc. No online
// softmax: p = exp(s*0.125 + bias - 6) is overflow-safe (see analysis),
// row-sum l via P*ones MFMA. Joint softmax == reference's logaddexp merge.
// ---------------------------------------------------------------------------
__global__ __launch_bounds__(256, 2) void attn_kernel(
        const float* __restrict__ query,
        const float* __restrict__ key,
        const float* __restrict__ value,
        const int* __restrict__ sampled,
        const int* __restrict__ q_idx,
        const int* __restrict__ k_idx,
        float* __restrict__ outp)
{
    const int qb = blockIdx.x;
    const int bh = blockIdx.y;
    const int t  = threadIdx.x;
    const int w    = t >> 6;       // wave 0..3 -> query rows w*64..w*64+63
    const int lane = t & 63;
    const int quad = lane >> 4;
    const int nrow = lane & 15;

    __shared__ _Float16 Kc[64 * PITCH];        // chunk keys, row-major [key][d]
    __shared__ _Float16 Vt[64 * PITCH];        // chunk values transposed [d][key]
    __shared__ _Float16 Pb[4][64 * PITCH];     // per-wave P / final O, [m][k]
    __shared__ int   s_row[512];               // gathered key rows (diag | sampled)
    __shared__ float lb[512];                  // per-key logit bias - 6
    __shared__ int   s_qi[256];                // original query rows (for unsort)
    __shared__ int   wb[4];

    const size_t bhN = (size_t)bh * NSEQ;

    // ---- setup: key gather lists, bias LUT ----
    {
        s_qi[t] = q_idx[bhN + qb * BLK + t];
        s_row[t] = k_idx[bhN + qb * BLK + t];            // diag keys
        int ss = sampled[bh * BLK + t];
        s_row[256 + t] = k_idx[bhN + ss];                // sampled keys
        int sb = ss >> 8;
        unsigned long long mk = __ballot(sb == qb);
        if (lane == 0) wb[w] = __popcll(mk);
        __syncthreads();
        int cnt_in = wb[0] + wb[1] + wb[2] + wb[3];
        float J = __logf((float)(NSEQ - BLK) / (float)(BLK - cnt_in));
        lb[t] = -6.0f;                                   // diag: bias 0, shift -6
        lb[256 + t] = (sb == qb) ? -1.0e4f : (J - 6.0f); // masked / rescaled
    }

    // ---- Q fragments (A-layout: m=lane&15, k=quad*8+j), f16, kept in regs ----
    v8h qf[4][2];
    #pragma unroll
    for (int mi = 0; mi < 4; ++mi) {
        int qi = q_idx[bhN + qb * BLK + w * 64 + mi * 16 + nrow];
        const float* qp = query + (bhN + (size_t)qi) * DDIM;
        #pragma unroll
        for (int kf = 0; kf < 2; ++kf) {
            const float4* q4 = (const float4*)(qp + kf * 32 + quad * 8);
            float4 x = q4[0], y = q4[1];
            v8h h;
            h[0]=(_Float16)x.x; h[1]=(_Float16)x.y; h[2]=(_Float16)x.z; h[3]=(_Float16)x.w;
            h[4]=(_Float16)y.x; h[5]=(_Float16)y.y; h[6]=(_Float16)y.z; h[7]=(_Float16)y.w;
            qf[mi][kf] = h;
        }
    }

    v4f Oacc[4][4];   // [mi][di], rows m=mi*16+quad*4+reg, col d=di*16+nrow
    v4f lacc[4];      // row sums
    #pragma unroll
    for (int mi = 0; mi < 4; ++mi) {
        lacc[mi] = (v4f){0.f, 0.f, 0.f, 0.f};
        #pragma unroll
        for (int di = 0; di < 4; ++di) Oacc[mi][di] = (v4f){0.f, 0.f, 0.f, 0.f};
    }
    const v8h ones = {(_Float16)1, (_Float16)1, (_Float16)1, (_Float16)1,
                      (_Float16)1, (_Float16)1, (_Float16)1, (_Float16)1};
    _Float16* Pw = Pb[w];

    for (int ch = 0; ch < 8; ++ch) {
        __syncthreads();
        // ---- stage K (row-major f16) ----
        {
            int r = t >> 2, seg = t & 3;
            int krow = s_row[ch * 64 + r];
            const float4* kp = (const float4*)(key + (bhN + (size_t)krow) * DDIM + seg * 16);
            float4 a0 = kp[0], a1 = kp[1], a2 = kp[2], a3 = kp[3];
            v8h h0, h1;
            h0[0]=(_Float16)a0.x; h0[1]=(_Float16)a0.y; h0[2]=(_Float16)a0.z; h0[3]=(_Float16)a0.w;
            h0[4]=(_Float16)a1.x; h0[5]=(_Float16)a1.y; h0[6]=(_Float16)a1.z; h0[7]=(_Float16)a1.w;
            h1[0]=(_Float16)a2.x; h1[1]=(_Float16)a2.y; h1[2]=(_Float16)a2.z; h1[3]=(_Float16)a2.w;
            h1[4]=(_Float16)a3.x; h1[5]=(_Float16)a3.y; h1[6]=(_Float16)a3.z; h1[7]=(_Float16)a3.w;
            *(v8h*)&Kc[r * PITCH + seg * 16] = h0;
            *(v8h*)&Kc[r * PITCH + seg * 16 + 8] = h1;
        }
        // ---- stage V transposed [d][key] ----
        {
            int vk = t & 63, dg = t >> 6;
            int vrow = s_row[ch * 64 + vk];
            const float4* vp = (const float4*)(value + (bhN + (size_t)vrow) * DDIM + dg * 16);
            float4 b0 = vp[0], b1 = vp[1], b2 = vp[2], b3 = vp[3];
            float tmp[16] = {b0.x,b0.y,b0.z,b0.w, b1.x,b1.y,b1.z,b1.w,
                             b2.x,b2.y,b2.z,b2.w, b3.x,b3.y,b3.z,b3.w};
            #pragma unroll
            for (int i = 0; i < 16; ++i)
                Vt[(dg * 16 + i) * PITCH + vk] = (_Float16)tmp[i];
        }
        __syncthreads();

        // ---- per-key bias for this chunk (col = ni*16 + nrow) ----
        float bb[4];
        #pragma unroll
        for (int ni = 0; ni < 4; ++ni) bb[ni] = lb[ch * 64 + ni * 16 + nrow];

        // ---- K B-frags and V B-frags ----
        v8h kf[4][2], vb[4][2];
        #pragma unroll
        for (int ni = 0; ni < 4; ++ni)
            #pragma unroll
            for (int k2 = 0; k2 < 2; ++k2) {
                kf[ni][k2] = *(const v8h*)&Kc[(ni * 16 + nrow) * PITCH + k2 * 32 + quad * 8];
                vb[ni][k2] = *(const v8h*)&Vt[(ni * 16 + nrow) * PITCH + k2 * 32 + quad * 8];
            }

        // ---- S = Q K^T, p = exp(S/8 + bias), write P (f16) ----
        #pragma unroll
        for (int mi = 0; mi < 4; ++mi) {
            v4f S[4];
            #pragma unroll
            for (int ni = 0; ni < 4; ++ni) {
                S[ni] = (v4f){0.f, 0.f, 0.f, 0.f};
                S[ni] = __builtin_amdgcn_mfma_f32_16x16x32_f16(qf[mi][0], kf[ni][0], S[ni], 0, 0, 0);
                S[ni] = __builtin_amdgcn_mfma_f32_16x16x32_f16(qf[mi][1], kf[ni][1], S[ni], 0, 0, 0);
            }
            #pragma unroll
            for (int ni = 0; ni < 4; ++ni) {
                #pragma unroll
                for (int r = 0; r < 4; ++r) {
                    float p = __expf(fmaf(S[ni][r], 0.125f, bb[ni]));
                    Pw[(mi * 16 + quad * 4 + r) * PITCH + ni * 16 + nrow] = (_Float16)p;
                }
            }
        }

        // ---- O += P V, l += P 1 ----
        #pragma unroll
        for (int mi = 0; mi < 4; ++mi) {
            #pragma unroll
            for (int k2 = 0; k2 < 2; ++k2) {
                v8h pa = *(const v8h*)&Pw[(mi * 16 + nrow) * PITCH + k2 * 32 + quad * 8];
                lacc[mi] = __builtin_amdgcn_mfma_f32_16x16x32_f16(pa, ones, lacc[mi], 0, 0, 0);
                #pragma unroll
                for (int di = 0; di < 4; ++di)
                    Oacc[mi][di] = __builtin_amdgcn_mfma_f32_16x16x32_f16(pa, vb[di][k2], Oacc[mi][di], 0, 0, 0);
            }
        }
    }

    // ---- normalize, stash O (f16) in P region, cooperative unsorted store ----
    #pragma unroll
    for (int mi = 0; mi < 4; ++mi)
        #pragma unroll
        for (int r = 0; r < 4; ++r) {
            float inv = 1.0f / lacc[mi][r];
            #pragma unroll
            for (int di = 0; di < 4; ++di)
                Pw[(mi * 16 + quad * 4 + r) * PITCH + di * 16 + nrow] =
                    (_Float16)(Oacc[mi][di][r] * inv);
        }
    __syncthreads();

    #pragma unroll
    for (int p = 0; p < 4; ++p) {
        int row = p * 64 + (t >> 2);
        int seg = t & 3;
        const _Float16* src = &Pb[row >> 6][(row & 63) * PITCH + seg * 16];
        v8h x0 = *(const v8h*)src;
        v8h x1 = *(const v8h*)(src + 8);
        int qi = s_qi[row];
        float4* op = (float4*)(outp + (bhN + (size_t)qi) * DDIM + seg * 16);
        op[0] = make_float4((float)x0[0], (float)x0[1], (float)x0[2], (float)x0[3]);
        op[1] = make_float4((float)x0[4], (float)x0[5], (float)x0[6], (float)x0[7]);
        op[2] = make_float4((float)x1[0], (float)x1[1], (float)x1[2], (float)x1[3]);
        op[3] = make_float4((float)x1[4], (float)x1[5], (float)x1[6], (float)x1[7]);
    }
}

// ---------------------------------------------------------------------------
extern "C" void kernel_launch(void* const* d_in, const int* in_sizes, int n_in,
                              void* d_out, int out_size, void* d_ws, size_t ws_size,
                              hipStream_t stream) {
    (void)in_sizes; (void)n_in; (void)out_size; (void)ws_size;
    const float* query = (const float*)d_in[0];
    const float* key   = (const float*)d_in[1];
    const float* value = (const float*)d_in[2];
    const float* proj  = (const float*)d_in[3];
    const int* sampled = (const int*)d_in[4];
    float* out = (float*)d_out;

    int* buckets = (int*)d_ws;
    int* q_idx   = buckets + 2 * BH * NSEQ;
    int* k_idx   = q_idx + BH * NSEQ;

    hash_kernel<<<dim3(BH * NSEQ / 64, 2), 256, 0, stream>>>(query, key, proj, buckets);
    sort_kernel<<<dim3(BH, 2), 64, 0, stream>>>(buckets, q_idx, k_idx);
    attn_kernel<<<dim3(NB, BH), 256, 0, stream>>>(query, key, value, sampled,
                                                  q_idx, k_idx, out);
}

// Round 3
// 299.650 us; speedup vs baseline: 3.8577x; 1.0133x over previous
//
#include <hip/hip_runtime.h>
#include <math.h>

#define BH    32      // B*H
#define NSEQ  8192
#define DDIM  64
#define NPROJ 7
#define BLK   256
#define NB    32      // NSEQ / BLK
#define PITCH 72      // f16 pitch for K/V/O rows (144 B, 16B-aligned)
#define PPITCH 40     // f16 pitch for P rows (32 keys + 8 pad)
#define LOG2E 1.44269504f
#define SC2   0.180336881f   // 0.125 * log2(e)

typedef _Float16 v8h __attribute__((ext_vector_type(8)));
typedef _Float16 v4h __attribute__((ext_vector_type(4)));
typedef float    v4f __attribute__((ext_vector_type(4)));

// ---------------------------------------------------------------------------
// Kernel 1: LSH hash, one row per thread. fp64 sign decisions (borderline
// signs are the only sort-mismatch hazard). Gray code = code ^ (code>>1).
// ---------------------------------------------------------------------------
__global__ __launch_bounds__(256) void hash_kernel(
        const float* __restrict__ query,
        const float* __restrict__ key,
        const float* __restrict__ proj,     // [64][7]
        int* __restrict__ buckets)          // [2][BH*NSEQ]
{
    const float* x = (blockIdx.y == 0) ? query : key;
    const int t = threadIdx.x;
    const int row = blockIdx.x * 256 + t;

    __shared__ double pdd[64 * NPROJ];
    for (int i = t; i < 64 * NPROJ; i += 256) pdd[i] = (double)proj[i];
    __syncthreads();

    const float4* rp = (const float4*)(x + (size_t)row * DDIM);
    double acc[NPROJ];
    #pragma unroll
    for (int r = 0; r < NPROJ; ++r) acc[r] = 0.0;

    #pragma unroll
    for (int i = 0; i < 16; ++i) {
        float4 v = rp[i];
        float e[4] = {v.x, v.y, v.z, v.w};
        #pragma unroll
        for (int c = 0; c < 4; ++c) {
            double xv = (double)e[c];
            const int d = i * 4 + c;
            #pragma unroll
            for (int r = 0; r < NPROJ; ++r)
                acc[r] += xv * pdd[d * NPROJ + r];
        }
    }
    int code = 0;
    #pragma unroll
    for (int r = 0; r < NPROJ; ++r)
        if (acc[r] > 0.0) code |= (1 << r);
    buckets[(size_t)blockIdx.y * (BH * NSEQ) + row] = code ^ (code >> 1);
}

// ---------------------------------------------------------------------------
// Kernel 2: stable counting sort, one 256-thread block per (tensor, bh).
// Thread t owns contiguous elems [t*32, t*32+32) (register-resident).
// cnt[v][t] u16 matrix (stride 258: (v + t/2)%32 banks -> conflict-free
// strided scans). Flat exclusive scan in (v-major, t-minor) order gives
// stable scatter positions.
// ---------------------------------------------------------------------------
#define SCNT 258
__global__ __launch_bounds__(256) void sort_kernel(
        const int* __restrict__ buckets,
        int* __restrict__ q_idx,
        int* __restrict__ k_idx)
{
    const int bh = blockIdx.x;
    const int t = threadIdx.x;
    const int lane = t & 63, w = t >> 6;
    const int* b = buckets + (size_t)blockIdx.y * (BH * NSEQ) + (size_t)bh * NSEQ;
    int* out = ((blockIdx.y == 0) ? q_idx : k_idx) + (size_t)bh * NSEQ;

    __shared__ unsigned short cnt[128 * SCNT];
    __shared__ unsigned int partial[256];
    __shared__ unsigned int wsum[4];

    unsigned int* cz = (unsigned int*)cnt;
    for (int i = t; i < 128 * SCNT / 2; i += 256) cz[i] = 0;

    int4 rv[8];
    const int4* b4 = (const int4*)b;
    #pragma unroll
    for (int s = 0; s < 8; ++s) rv[s] = b4[t * 8 + s];
    __syncthreads();

    #pragma unroll
    for (int s = 0; s < 8; ++s) {
        cnt[rv[s].x * SCNT + t]++;
        cnt[rv[s].y * SCNT + t]++;
        cnt[rv[s].z * SCNT + t]++;
        cnt[rv[s].w * SCNT + t]++;
    }
    __syncthreads();

    const int v0 = t >> 1, tt0 = (t & 1) * 128;
    {
        unsigned int s = 0;
        for (int j = 0; j < 128; ++j) s += cnt[v0 * SCNT + tt0 + j];
        partial[t] = s;
    }
    __syncthreads();

    unsigned int chunkoff;
    {
        unsigned int x = partial[t], own = x;
        #pragma unroll
        for (int d = 1; d < 64; d <<= 1) {
            unsigned int y = __shfl_up(x, d);
            if (lane >= d) x += y;
        }
        if (lane == 63) wsum[w] = x;
        __syncthreads();
        unsigned int wb0 = 0;
        if (w == 1) wb0 = wsum[0];
        else if (w == 2) wb0 = wsum[0] + wsum[1];
        else if (w == 3) wb0 = wsum[0] + wsum[1] + wsum[2];
        chunkoff = x - own + wb0;
    }

    {
        unsigned int s = chunkoff;
        for (int j = 0; j < 128; ++j) {
            unsigned short c = cnt[v0 * SCNT + tt0 + j];
            cnt[v0 * SCNT + tt0 + j] = (unsigned short)s;
            s += c;
        }
    }
    __syncthreads();

    const int i0 = t * 32;
    #pragma unroll
    for (int s = 0; s < 8; ++s) {
        int4 q = rv[s];
        int j4 = i0 + s * 4;
        { unsigned short p = cnt[q.x * SCNT + t]++; out[p] = j4 + 0; }
        { unsigned short p = cnt[q.y * SCNT + t]++; out[p] = j4 + 1; }
        { unsigned short p = cnt[q.z * SCNT + t]++; out[p] = j4 + 2; }
        { unsigned short p = cnt[q.w * SCNT + t]++; out[p] = j4 + 3; }
    }
}

// ---------------------------------------------------------------------------
// Kernel 3: MFMA attention, transposed dataflow.
//   S^T = K . Q^T   (C-layout: row=key, col=query -> P stored [q][k], b64)
//   O^T = V^T . P^T (A=V^T from Vt[d][key], B=P^T from P[q][k], both b128)
//   l   = ones . P^T (every acc row holds l[q])
// Joint softmax over diag+sampled keys == reference's logaddexp merge.
// exp2-domain: p = exp2(S*0.125*log2e + lb2[key]),  lb2 pre-scaled.
// ---------------------------------------------------------------------------
__global__ __launch_bounds__(256, 3) void attn_kernel(
        const float* __restrict__ query,
        const float* __restrict__ key,
        const float* __restrict__ value,
        const int* __restrict__ sampled,
        const int* __restrict__ q_idx,
        const int* __restrict__ k_idx,
        float* __restrict__ outp)
{
    const int qb = blockIdx.x;
    const int bh = blockIdx.y;
    const int t  = threadIdx.x;
    const int w    = t >> 6;       // wave -> queries [w*64, w*64+64)
    const int lane = t & 63;
    const int quad = lane >> 4;
    const int nrow = lane & 15;

    __shared__ __align__(16) unsigned char smem[38912];
    _Float16* Kc = (_Float16*)smem;                 // 64*72*2   = 9216 B
    _Float16* Vt = (_Float16*)(smem + 9216);        // 64*72*2   = 9216 B
    _Float16* Pb = (_Float16*)(smem + 18432);       // 4*64*40*2 = 20480 B
    _Float16* Ob = (_Float16*)smem;                 // epilogue: 256*72*2 = 36864 B
    __shared__ int s_row[512];
    __shared__ __align__(16) float lb[512];
    __shared__ int s_qi[256];
    __shared__ int wb[4];

    const size_t bhN = (size_t)bh * NSEQ;

    // ---- setup ----
    {
        s_qi[t] = q_idx[bhN + qb * BLK + t];
        s_row[t] = k_idx[bhN + qb * BLK + t];
        int ss = sampled[bh * BLK + t];
        s_row[256 + t] = k_idx[bhN + ss];
        int sb = ss >> 8;
        unsigned long long mk = __ballot(sb == qb);
        if (lane == 0) wb[w] = __popcll(mk);
        __syncthreads();
        int cnt_in = wb[0] + wb[1] + wb[2] + wb[3];
        float J = __logf((float)(NSEQ - BLK) / (float)(BLK - cnt_in));
        lb[t] = -6.0f * LOG2E;
        lb[256 + t] = (sb == qb) ? -3.0e4f : (J - 6.0f) * LOG2E;
    }

    // ---- Q fragments (per-lane: Q[w*64+ni*16+nrow][k2*32+quad*8+j]) ----
    v8h qf[4][2];
    #pragma unroll
    for (int ni = 0; ni < 4; ++ni) {
        int qi = s_qi[w * 64 + ni * 16 + nrow];
        const float* qp = query + (bhN + (size_t)qi) * DDIM;
        #pragma unroll
        for (int k2 = 0; k2 < 2; ++k2) {
            const float4* q4 = (const float4*)(qp + k2 * 32 + quad * 8);
            float4 a = q4[0], bvec = q4[1];
            v8h h;
            h[0]=(_Float16)a.x; h[1]=(_Float16)a.y; h[2]=(_Float16)a.z; h[3]=(_Float16)a.w;
            h[4]=(_Float16)bvec.x; h[5]=(_Float16)bvec.y; h[6]=(_Float16)bvec.z; h[7]=(_Float16)bvec.w;
            qf[ni][k2] = h;
        }
    }

    v4f Oacc[4][4];   // [d-tile][q-tile]: O^T rows d=mi2*16+quad*4+r, col q=ni*16+nrow
    v4f lacc[4];
    #pragma unroll
    for (int ni = 0; ni < 4; ++ni) {
        lacc[ni] = (v4f){0.f, 0.f, 0.f, 0.f};
        #pragma unroll
        for (int mi2 = 0; mi2 < 4; ++mi2) Oacc[mi2][ni] = (v4f){0.f, 0.f, 0.f, 0.f};
    }
    const v8h ones = {(_Float16)1, (_Float16)1, (_Float16)1, (_Float16)1,
                      (_Float16)1, (_Float16)1, (_Float16)1, (_Float16)1};
    _Float16* Pw = Pb + w * 64 * PPITCH;

    for (int ch = 0; ch < 8; ++ch) {
        __syncthreads();
        // ---- stage K row-major [key][d] ----
        {
            int r = t >> 2, seg = t & 3;
            int kr = s_row[ch * 64 + r];
            const float4* kp = (const float4*)(key + (bhN + (size_t)kr) * DDIM + seg * 16);
            float4 a0 = kp[0], a1 = kp[1], a2 = kp[2], a3 = kp[3];
            v8h h0, h1;
            h0[0]=(_Float16)a0.x; h0[1]=(_Float16)a0.y; h0[2]=(_Float16)a0.z; h0[3]=(_Float16)a0.w;
            h0[4]=(_Float16)a1.x; h0[5]=(_Float16)a1.y; h0[6]=(_Float16)a1.z; h0[7]=(_Float16)a1.w;
            h1[0]=(_Float16)a2.x; h1[1]=(_Float16)a2.y; h1[2]=(_Float16)a2.z; h1[3]=(_Float16)a2.w;
            h1[4]=(_Float16)a3.x; h1[5]=(_Float16)a3.y; h1[6]=(_Float16)a3.z; h1[7]=(_Float16)a3.w;
            *(v8h*)&Kc[r * PITCH + seg * 16] = h0;
            *(v8h*)&Kc[r * PITCH + seg * 16 + 8] = h1;
        }
        // ---- stage V transposed [d][key] with packed b64 writes ----
        {
            int kq = t & 15, dg = t >> 4;
            float la[4][4];
            #pragma unroll
            for (int c = 0; c < 4; ++c) {
                int vr = s_row[ch * 64 + kq * 4 + c];
                float4 v = *(const float4*)(value + (bhN + (size_t)vr) * DDIM + dg * 4);
                la[c][0] = v.x; la[c][1] = v.y; la[c][2] = v.z; la[c][3] = v.w;
            }
            #pragma unroll
            for (int dd = 0; dd < 4; ++dd) {
                v4h h;
                h[0]=(_Float16)la[0][dd]; h[1]=(_Float16)la[1][dd];
                h[2]=(_Float16)la[2][dd]; h[3]=(_Float16)la[3][dd];
                *(v4h*)&Vt[(dg * 4 + dd) * PITCH + kq * 4] = h;
            }
        }
        __syncthreads();

        #pragma unroll
        for (int ks = 0; ks < 2; ++ks) {
            // ---- S^T = K.Q^T over 32 keys, exp, store P[q][k] (b64) ----
            #pragma unroll
            for (int mi = 0; mi < 2; ++mi) {
                v4f bb = *(const v4f*)&lb[ch * 64 + ks * 32 + mi * 16 + quad * 4];
                const int krow = ks * 32 + mi * 16 + nrow;
                v8h ka0 = *(const v8h*)&Kc[krow * PITCH + quad * 8];
                v8h ka1 = *(const v8h*)&Kc[krow * PITCH + 32 + quad * 8];
                #pragma unroll
                for (int ni = 0; ni < 4; ++ni) {
                    v4f S = (v4f){0.f, 0.f, 0.f, 0.f};
                    S = __builtin_amdgcn_mfma_f32_16x16x32_f16(ka0, qf[ni][0], S, 0, 0, 0);
                    S = __builtin_amdgcn_mfma_f32_16x16x32_f16(ka1, qf[ni][1], S, 0, 0, 0);
                    v4h ph;
                    #pragma unroll
                    for (int r = 0; r < 4; ++r)
                        ph[r] = (_Float16)__builtin_amdgcn_exp2f(fmaf(S[r], SC2, bb[r]));
                    *(v4h*)&Pw[(ni * 16 + nrow) * PPITCH + mi * 16 + quad * 4] = ph;
                }
            }
            // ---- load P^T frags, accumulate l and O^T ----
            v8h pbv[4];
            #pragma unroll
            for (int ni = 0; ni < 4; ++ni) {
                pbv[ni] = *(const v8h*)&Pw[(ni * 16 + nrow) * PPITCH + quad * 8];
                lacc[ni] = __builtin_amdgcn_mfma_f32_16x16x32_f16(ones, pbv[ni], lacc[ni], 0, 0, 0);
            }
            #pragma unroll
            for (int mi2 = 0; mi2 < 4; ++mi2) {
                v8h va = *(const v8h*)&Vt[(mi2 * 16 + nrow) * PITCH + ks * 32 + quad * 8];
                #pragma unroll
                for (int ni = 0; ni < 4; ++ni)
                    Oacc[mi2][ni] = __builtin_amdgcn_mfma_f32_16x16x32_f16(va, pbv[ni], Oacc[mi2][ni], 0, 0, 0);
            }
        }
    }

    // ---- normalize, write O (f16) to [q][d] pool, cooperative scatter ----
    __syncthreads();
    #pragma unroll
    for (int ni = 0; ni < 4; ++ni) {
        float inv = 1.0f / lacc[ni][0];
        #pragma unroll
        for (int mi2 = 0; mi2 < 4; ++mi2) {
            v4h h;
            #pragma unroll
            for (int r = 0; r < 4; ++r)
                h[r] = (_Float16)(Oacc[mi2][ni][r] * inv);
            *(v4h*)&Ob[(w * 64 + ni * 16 + nrow) * PITCH + mi2 * 16 + quad * 4] = h;
        }
    }
    __syncthreads();

    #pragma unroll
    for (int p = 0; p < 4; ++p) {
        int row = p * 64 + (t >> 2);
        int seg = t & 3;
        const _Float16* src = &Ob[row * PITCH + seg * 16];
        v8h x0 = *(const v8h*)src;
        v8h x1 = *(const v8h*)(src + 8);
        int qi = s_qi[row];
        float4* op = (float4*)(outp + (bhN + (size_t)qi) * DDIM + seg * 16);
        op[0] = make_float4((float)x0[0], (float)x0[1], (float)x0[2], (float)x0[3]);
        op[1] = make_float4((float)x0[4], (float)x0[5], (float)x0[6], (float)x0[7]);
        op[2] = make_float4((float)x1[0], (float)x1[1], (float)x1[2], (float)x1[3]);
        op[3] = make_float4((float)x1[4], (float)x1[5], (float)x1[6], (float)x1[7]);
    }
}

// ---------------------------------------------------------------------------
extern "C" void kernel_launch(void* const* d_in, const int* in_sizes, int n_in,
                              void* d_out, int out_size, void* d_ws, size_t ws_size,
                              hipStream_t stream) {
    (void)in_sizes; (void)n_in; (void)out_size; (void)ws_size;
    const float* query = (const float*)d_in[0];
    const float* key   = (const float*)d_in[1];
    const float* value = (const float*)d_in[2];
    const float* proj  = (const float*)d_in[3];
    const int* sampled = (const int*)d_in[4];
    float* out = (float*)d_out;

    int* buckets = (int*)d_ws;
    int* q_idx   = buckets + 2 * BH * NSEQ;
    int* k_idx   = q_idx + BH * NSEQ;

    hash_kernel<<<dim3(BH * NSEQ / 256, 2), 256, 0, stream>>>(query, key, proj, buckets);
    sort_kernel<<<dim3(BH, 2), 256, 0, stream>>>(buckets, q_idx, k_idx);
    attn_kernel<<<dim3(NB, BH), 256, 0, stream>>>(query, key, value, sampled,
                                                  q_idx, k_idx, out);
}